// Round 1
// 271.757 us; speedup vs baseline: 1.0336x; 1.0336x over previous
//
#include <hip/hip_runtime.h>

typedef unsigned short u16;
typedef short bf16x8 __attribute__((ext_vector_type(8)));
typedef float f32x4 __attribute__((ext_vector_type(4)));

#define D_IN 2048
#define H_DIM 2048
#define K_CH 4096

__device__ __forceinline__ u16 f2bf(float f) {
  unsigned int u = __float_as_uint(f);
  u += 0x7fffu + ((u >> 16) & 1u);   // round-to-nearest-even
  return (u16)(u >> 16);
}
__device__ __forceinline__ float sigmoidf(float x) {
  return 1.0f / (1.0f + __expf(-x));
}
__device__ __forceinline__ uint4 packrow(float4 a, float4 b) {
  uint4 w;
  w.x = (unsigned)f2bf(a.x) | ((unsigned)f2bf(a.y) << 16);
  w.y = (unsigned)f2bf(a.z) | ((unsigned)f2bf(a.w) << 16);
  w.z = (unsigned)f2bf(b.x) | ((unsigned)f2bf(b.y) << 16);
  w.w = (unsigned)f2bf(b.z) | ((unsigned)f2bf(b.w) << 16);
  return w;
}

// ---------------------------------------------------------------------------
// K1 (fused prep, 2049 blocks):
//  blocks 0..1023:   4 rows of children_h: column-sum partials + bf16 convert
//  blocks 1024..1535: wfhb = bf16(W_fh), 8192 elems/block
//  blocks 1536..2047: g[h] = W_fx[h]·x + b_fx + b_fh  (1 wave/row, 4 rows/blk)
//  block  2048:      zero hsum[2048] + accv[2048] (replaces hipMemsetAsync)
// ---------------------------------------------------------------------------
__global__ __launch_bounds__(256) void k1(
    const float* __restrict__ ch, const float* __restrict__ wfh,
    const float* __restrict__ Wfx, const float* __restrict__ bfx,
    const float* __restrict__ bfh, const float* __restrict__ x,
    float* __restrict__ partials, u16* __restrict__ chb,
    u16* __restrict__ wfhb, float* __restrict__ g,
    float* __restrict__ hsum, float* __restrict__ accv) {
  const int t = threadIdx.x;
  const int bid = blockIdx.x;
  if (bid < 1024) {
    const int r0 = bid * 4;
    float4 a[4], b[4];
#pragma unroll
    for (int r = 0; r < 4; ++r) {
      const float4* p = (const float4*)(ch + (size_t)(r0 + r) * H_DIM + t * 8);
      a[r] = p[0];
      b[r] = p[1];
    }
    float s0 = 0.f, s1 = 0.f, s2 = 0.f, s3 = 0.f;
    float s4 = 0.f, s5 = 0.f, s6 = 0.f, s7 = 0.f;
#pragma unroll
    for (int r = 0; r < 4; ++r) {
      s0 += a[r].x; s1 += a[r].y; s2 += a[r].z; s3 += a[r].w;
      s4 += b[r].x; s5 += b[r].y; s6 += b[r].z; s7 += b[r].w;
      *(uint4*)(chb + (size_t)(r0 + r) * H_DIM + t * 8) = packrow(a[r], b[r]);
    }
    float4 lo, hi;
    lo.x = s0; lo.y = s1; lo.z = s2; lo.w = s3;
    hi.x = s4; hi.y = s5; hi.z = s6; hi.w = s7;
    float* pp = partials + (size_t)bid * H_DIM + t * 8;
    *(float4*)pp = lo;
    *(float4*)(pp + 4) = hi;
  } else if (bid < 1536) {
    const size_t base = (size_t)(bid - 1024) * 8192 + t * 8;
    float4 a[4], b[4];
#pragma unroll
    for (int j = 0; j < 4; ++j) {
      const float4* p = (const float4*)(wfh + base + j * 2048);
      a[j] = p[0];
      b[j] = p[1];
    }
#pragma unroll
    for (int j = 0; j < 4; ++j)
      *(uint4*)(wfhb + base + j * 2048) = packrow(a[j], b[j]);
  } else if (bid < 2048) {
    const int wave = t >> 6, lane = t & 63;
    const int h = (bid - 1536) * 4 + wave;  // 0..2047
    const float4* w = (const float4*)(Wfx + (size_t)h * D_IN);
    const float4* xv = (const float4*)x;
    float s = 0.f;
#pragma unroll
    for (int i = 0; i < 8; ++i) {
      int idx = i * 64 + lane;
      float4 av = w[idx], bv = xv[idx];
      s += av.x * bv.x + av.y * bv.y + av.z * bv.z + av.w * bv.w;
    }
#pragma unroll
    for (int off = 32; off > 0; off >>= 1) s += __shfl_xor(s, off);
    if (lane == 0) g[h] = s + bfx[h] + bfh[h];
  } else {
    float4 z = {0.f, 0.f, 0.f, 0.f};
    ((float4*)hsum)[t * 2] = z;
    ((float4*)hsum)[t * 2 + 1] = z;
    ((float4*)accv)[t * 2] = z;
    ((float4*)accv)[t * 2 + 1] = z;
  }
}

// ---------------------------------------------------------------------------
// K2: hsum reduction over partials (unchanged). Grid (8 col-groups, 8
// p-groups) = 64 blocks; each thread sums 128 partials, one atomicAdd.
// ---------------------------------------------------------------------------
__global__ __launch_bounds__(256) void kred(const float* __restrict__ partials,
                                            float* __restrict__ hsum) {
  const int c = blockIdx.x * 256 + threadIdx.x;
  const int p0 = blockIdx.y * 128;
  float a0 = 0.f, a1 = 0.f, a2 = 0.f, a3 = 0.f;
  float a4 = 0.f, a5 = 0.f, a6 = 0.f, a7 = 0.f;
  for (int p = p0; p < p0 + 128; p += 8) {
    a0 += partials[(size_t)(p + 0) * H_DIM + c];
    a1 += partials[(size_t)(p + 1) * H_DIM + c];
    a2 += partials[(size_t)(p + 2) * H_DIM + c];
    a3 += partials[(size_t)(p + 3) * H_DIM + c];
    a4 += partials[(size_t)(p + 4) * H_DIM + c];
    a5 += partials[(size_t)(p + 5) * H_DIM + c];
    a6 += partials[(size_t)(p + 6) * H_DIM + c];
    a7 += partials[(size_t)(p + 7) * H_DIM + c];
  }
  float s = ((a0 + a1) + (a2 + a3)) + ((a4 + a5) + (a6 + a7));
  atomicAdd(hsum + c, s);
}

// ---------------------------------------------------------------------------
// K3 (fused, 2048 blocks, block-role specialization):
//  blocks 0..511:    bf16 GEMM + sigmoid + weighted K-reduction (128x128 tile,
//                    BK=64, XOR chunk swizzle) — identical inner loop to the
//                    verified kgemm; bm = bid&31, bn = bid>>5.
//  blocks 512..2047: iou matvec (1 wave/row, rows 0..6143) — needs hsum.
//  Co-residency: ~2 GEMM + ~3 matvec blocks per CU; the 96 MB matvec stream
//  hides the GEMM's barrier-drain latency (m114 MFMA/VALU co-scheduling).
// ---------------------------------------------------------------------------
#define BM 128
#define BN 128
#define BK 64

__global__ __launch_bounds__(256) void k3(
    const u16* __restrict__ chb, const float* __restrict__ cc,
    const u16* __restrict__ wfhb, const float* __restrict__ g,
    float* __restrict__ accv, const float* __restrict__ Wix,
    const float* __restrict__ bix, const float* __restrict__ Wih,
    const float* __restrict__ bih, const float* __restrict__ x,
    const float* __restrict__ hsum, float* __restrict__ iou) {
  __shared__ u16 As[BM * BK];  // row stride 64 u16 (128 B), 8 chunks of 16 B
  __shared__ u16 Bs[BN * BK];

  const int bid = blockIdx.x;
  const int t = threadIdx.x;
  const int wave = t >> 6, lane = t & 63;

  if (bid < 512) {
    const int lrow = lane & 15, lquad = lane >> 4;
    const int wm = wave >> 1, wn = wave & 1;
    const int row0 = (bid & 31) * BM;
    const int col0 = (bid >> 5) * BN;

    f32x4 acc[4][4] = {};

    const int srow = lane >> 3;           // row within the 8-row group
    const int schunk = (lane & 7) ^ srow; // XOR-swizzled source chunk
    const u16* agbase = chb  + (size_t)(row0 + wave * 32 + srow) * H_DIM + schunk * 8;
    const u16* bgbase = wfhb + (size_t)(col0 + wave * 32 + srow) * H_DIM + schunk * 8;

    for (int kb = 0; kb < D_IN / BK; ++kb) {
      __syncthreads();
#pragma unroll
      for (int i = 0; i < 4; ++i)
        __builtin_amdgcn_global_load_lds(
            (const __attribute__((address_space(1))) void*)(agbase + (size_t)i * 8 * H_DIM + kb * BK),
            (__attribute__((address_space(3))) void*)(As + (wave * 32 + i * 8) * 64),
            16, 0, 0);
#pragma unroll
      for (int i = 0; i < 4; ++i)
        __builtin_amdgcn_global_load_lds(
            (const __attribute__((address_space(1))) void*)(bgbase + (size_t)i * 8 * H_DIM + kb * BK),
            (__attribute__((address_space(3))) void*)(Bs + (wave * 32 + i * 8) * 64),
            16, 0, 0);
      __syncthreads();

#pragma unroll
      for (int step = 0; step < 2; ++step) {
        const int slot = ((step * 4 + lquad) ^ (lrow & 7)) * 8;
        bf16x8 fa[4], fb[4];
#pragma unroll
        for (int i = 0; i < 4; ++i)
          fa[i] = *(const bf16x8*)(As + (wm * 64 + i * 16 + lrow) * 64 + slot);
#pragma unroll
        for (int i = 0; i < 4; ++i)
          fb[i] = *(const bf16x8*)(Bs + (wn * 64 + i * 16 + lrow) * 64 + slot);
#pragma unroll
        for (int mi = 0; mi < 4; ++mi)
#pragma unroll
          for (int ni = 0; ni < 4; ++ni)
            acc[mi][ni] = __builtin_amdgcn_mfma_f32_16x16x32_bf16(
                fa[mi], fb[ni], acc[mi][ni], 0, 0, 0);
      }
    }

    // Epilogue. C/D layout: col = lane&15, row = (lane>>4)*4 + reg.
#pragma unroll
    for (int ni = 0; ni < 4; ++ni) {
      const int colg = col0 + wn * 64 + ni * 16 + lrow;
      const float gv = g[colg];
      float s = 0.f;
#pragma unroll
      for (int mi = 0; mi < 4; ++mi) {
        const int rowg = row0 + wm * 64 + mi * 16 + lquad * 4;
#pragma unroll
        for (int r = 0; r < 4; ++r) {
          float f = sigmoidf(gv + acc[mi][ni][r]);
          s += f * cc[(size_t)(rowg + r) * H_DIM + colg];
        }
      }
      s += __shfl_xor(s, 16);
      s += __shfl_xor(s, 32);
      if (lquad == 0) atomicAdd(accv + colg, s);
    }
  } else {
    const int row = (bid - 512) * 4 + wave;  // 0..6143
    const float4* wx = (const float4*)(Wix + (size_t)row * D_IN);
    const float4* wh = (const float4*)(Wih + (size_t)row * H_DIM);
    const float4* xv = (const float4*)x;
    const float4* hv = (const float4*)hsum;
    float s = 0.f;
#pragma unroll
    for (int i = 0; i < 8; ++i) {
      int idx = i * 64 + lane;
      float4 a = wx[idx], b = xv[idx];
      s += a.x * b.x + a.y * b.y + a.z * b.z + a.w * b.w;
      float4 c = wh[idx], d = hv[idx];
      s += c.x * d.x + c.y * d.y + c.z * d.z + c.w * d.w;
    }
#pragma unroll
    for (int off = 32; off > 0; off >>= 1) s += __shfl_xor(s, off);
    if (lane == 0) iou[row] = s + bix[row] + bih[row];
  }
}

// ---------------------------------------------------------------------------
// K4: finalize (fp32 out, unchanged).
// ---------------------------------------------------------------------------
__global__ __launch_bounds__(256) void kfinal(const float* __restrict__ iou,
                                              const float* __restrict__ accv,
                                              float* __restrict__ out) {
  const int h = blockIdx.x * 256 + threadIdx.x;
  float si = sigmoidf(iou[h]);
  float so = sigmoidf(iou[H_DIM + h]);
  float tu = tanhf(iou[2 * H_DIM + h]);
  float c = si * tu + accv[h];
  float hh = so * tanhf(c);
  out[h] = so;
  out[H_DIM + h] = c;
  out[2 * H_DIM + h] = hh;
}

extern "C" void kernel_launch(void* const* d_in, const int* in_sizes, int n_in,
                              void* d_out, int out_size, void* d_ws, size_t ws_size,
                              hipStream_t stream) {
  const float* x   = (const float*)d_in[0];   // input [2048]
  const float* cc  = (const float*)d_in[1];   // children_c [4096,2048]
  const float* ch  = (const float*)d_in[2];   // children_h [4096,2048]
  const float* Wix = (const float*)d_in[3];   // W_iou_x [6144,2048]
  const float* bix = (const float*)d_in[4];   // b_iou_x [6144]
  const float* Wih = (const float*)d_in[5];   // W_iou_h [6144,2048]
  const float* bih = (const float*)d_in[6];   // b_iou_h [6144]
  const float* Wfx = (const float*)d_in[7];   // W_fx [2048,2048]
  const float* bfx = (const float*)d_in[8];   // b_fx [2048]
  const float* Wfh = (const float*)d_in[9];   // W_fh [2048,2048]
  const float* bfh = (const float*)d_in[10];  // b_fh [2048]

  float* ws   = (float*)d_ws;
  float* hsum = ws;                    // [2048]  (zeroed in k1; kred atomics)
  float* iou  = ws + 2048;             // [6144]
  float* g    = ws + 8192;             // [2048]
  float* accv = ws + 10240;            // [2048]  (zeroed in k1; k3 atomics)
  float* partials = ws + 12288;        // [1024 * 2048]
  u16* chb  = (u16*)(ws + 12288 + 1024 * 2048);  // [4096*2048] bf16
  u16* wfhb = chb + (size_t)K_CH * H_DIM;        // [2048*2048] bf16
  float* out = (float*)d_out;

  k1<<<2049, 256, 0, stream>>>(ch, Wfh, Wfx, bfx, bfh, x, partials, chb, wfhb, g, hsum, accv);
  kred<<<dim3(8, 8), 256, 0, stream>>>(partials, hsum);
  k3<<<2048, 256, 0, stream>>>(chb, cc, wfhb, g, accv, Wix, bix, Wih, bih, x, hsum, iou);
  kfinal<<<8, 256, 0, stream>>>(iou, accv, out);
}

// Round 2
// 264.718 us; speedup vs baseline: 1.0611x; 1.0266x over previous
//
#include <hip/hip_runtime.h>

typedef unsigned short u16;
typedef short bf16x8 __attribute__((ext_vector_type(8)));
typedef float f32x4 __attribute__((ext_vector_type(4)));

#define D_IN 2048
#define H_DIM 2048
#define K_CH 4096

__device__ __forceinline__ u16 f2bf(float f) {
  unsigned int u = __float_as_uint(f);
  u += 0x7fffu + ((u >> 16) & 1u);   // round-to-nearest-even
  return (u16)(u >> 16);
}
__device__ __forceinline__ float sigmoidf(float x) {
  return 1.0f / (1.0f + __expf(-x));
}
__device__ __forceinline__ uint4 packrow(float4 a, float4 b) {
  uint4 w;
  w.x = (unsigned)f2bf(a.x) | ((unsigned)f2bf(a.y) << 16);
  w.y = (unsigned)f2bf(a.z) | ((unsigned)f2bf(a.w) << 16);
  w.z = (unsigned)f2bf(b.x) | ((unsigned)f2bf(b.y) << 16);
  w.w = (unsigned)f2bf(b.z) | ((unsigned)f2bf(b.w) << 16);
  return w;
}

// ---------------------------------------------------------------------------
// K1 (fused prep, 3585 blocks, all roles LDS-free / high occupancy):
//  [0,1024):    4 rows of children_h: column-sum partials + bf16 convert
//  [1024,1536): wfhb = bf16(W_fh), 8192 elems/block
//  [1536,2048): g[h] = W_fx[h]·x + b_fx + b_fh    (1 wave/row)
//  [2048,3584): ioux[row] = W_iou_x[row]·x + b_iou_x + b_iou_h (1 wave/row)
//  3584:        zero hsum[2048] + accv[2048]
// ---------------------------------------------------------------------------
__global__ __launch_bounds__(256) void k1(
    const float* __restrict__ ch, const float* __restrict__ wfh,
    const float* __restrict__ Wfx, const float* __restrict__ bfx,
    const float* __restrict__ bfh, const float* __restrict__ x,
    const float* __restrict__ Wix, const float* __restrict__ bix,
    const float* __restrict__ bih, float* __restrict__ partials,
    u16* __restrict__ chb, u16* __restrict__ wfhb, float* __restrict__ g,
    float* __restrict__ ioux, float* __restrict__ hsum,
    float* __restrict__ accv) {
  const int t = threadIdx.x;
  const int bid = blockIdx.x;
  if (bid < 1024) {
    const int r0 = bid * 4;
    float4 a[4], b[4];
#pragma unroll
    for (int r = 0; r < 4; ++r) {
      const float4* p = (const float4*)(ch + (size_t)(r0 + r) * H_DIM + t * 8);
      a[r] = p[0];
      b[r] = p[1];
    }
    float s0 = 0.f, s1 = 0.f, s2 = 0.f, s3 = 0.f;
    float s4 = 0.f, s5 = 0.f, s6 = 0.f, s7 = 0.f;
#pragma unroll
    for (int r = 0; r < 4; ++r) {
      s0 += a[r].x; s1 += a[r].y; s2 += a[r].z; s3 += a[r].w;
      s4 += b[r].x; s5 += b[r].y; s6 += b[r].z; s7 += b[r].w;
      *(uint4*)(chb + (size_t)(r0 + r) * H_DIM + t * 8) = packrow(a[r], b[r]);
    }
    float4 lo, hi;
    lo.x = s0; lo.y = s1; lo.z = s2; lo.w = s3;
    hi.x = s4; hi.y = s5; hi.z = s6; hi.w = s7;
    float* pp = partials + (size_t)bid * H_DIM + t * 8;
    *(float4*)pp = lo;
    *(float4*)(pp + 4) = hi;
  } else if (bid < 1536) {
    const size_t base = (size_t)(bid - 1024) * 8192 + t * 8;
    float4 a[4], b[4];
#pragma unroll
    for (int j = 0; j < 4; ++j) {
      const float4* p = (const float4*)(wfh + base + j * 2048);
      a[j] = p[0];
      b[j] = p[1];
    }
#pragma unroll
    for (int j = 0; j < 4; ++j)
      *(uint4*)(wfhb + base + j * 2048) = packrow(a[j], b[j]);
  } else if (bid < 2048) {
    const int wave = t >> 6, lane = t & 63;
    const int h = (bid - 1536) * 4 + wave;  // 0..2047
    const float4* w = (const float4*)(Wfx + (size_t)h * D_IN);
    const float4* xv = (const float4*)x;
    float s = 0.f;
#pragma unroll
    for (int i = 0; i < 8; ++i) {
      int idx = i * 64 + lane;
      float4 av = w[idx], bv = xv[idx];
      s += av.x * bv.x + av.y * bv.y + av.z * bv.z + av.w * bv.w;
    }
#pragma unroll
    for (int off = 32; off > 0; off >>= 1) s += __shfl_xor(s, off);
    if (lane == 0) g[h] = s + bfx[h] + bfh[h];
  } else if (bid < 3584) {
    const int wave = t >> 6, lane = t & 63;
    const int row = (bid - 2048) * 4 + wave;  // 0..6143
    const float4* w = (const float4*)(Wix + (size_t)row * D_IN);
    const float4* xv = (const float4*)x;
    float s = 0.f;
#pragma unroll
    for (int i = 0; i < 8; ++i) {
      int idx = i * 64 + lane;
      float4 av = w[idx], bv = xv[idx];
      s += av.x * bv.x + av.y * bv.y + av.z * bv.z + av.w * bv.w;
    }
#pragma unroll
    for (int off = 32; off > 0; off >>= 1) s += __shfl_xor(s, off);
    if (lane == 0) ioux[row] = s + bix[row] + bih[row];
  } else {
    float4 z = {0.f, 0.f, 0.f, 0.f};
    ((float4*)hsum)[t * 2] = z;
    ((float4*)hsum)[t * 2 + 1] = z;
    ((float4*)accv)[t * 2] = z;
    ((float4*)accv)[t * 2 + 1] = z;
  }
}

// ---------------------------------------------------------------------------
// kG (576 blocks):
//  [0,64):   hsum reduction over partials (kred role, no LDS; depends only
//            on k1, so it can share the dispatch with the GEMM).
//  [64,576): bf16 GEMM + sigmoid + weighted K-reduction. 128x128 tile,
//            BK=64, XOR chunk swizzle, NOW 2-phase double-buffered:
//            stage tile kb+1 into buf^1 BEFORE computing buf (T3 minimal
//            recipe) — one __syncthreads per K-step; its implicit vmcnt(0)
//            is the depth-1 pipeline drain. LDS 64 KiB -> 2 blocks/CU.
// ---------------------------------------------------------------------------
#define BM 128
#define BN 128
#define BK 64

__global__ __launch_bounds__(256) void kG(
    const u16* __restrict__ chb, const float* __restrict__ cc,
    const u16* __restrict__ wfhb, const float* __restrict__ g,
    const float* __restrict__ partials, float* __restrict__ hsum,
    float* __restrict__ accv) {
  __shared__ u16 As[2][BM * BK];  // row stride 64 u16 (128 B)
  __shared__ u16 Bs[2][BN * BK];

  const int bid = blockIdx.x;
  const int t = threadIdx.x;

  if (bid < 64) {
    // --- kred role ---
    const int c = (bid & 7) * 256 + t;
    const int p0 = (bid >> 3) * 128;
    float a0 = 0.f, a1 = 0.f, a2 = 0.f, a3 = 0.f;
    float a4 = 0.f, a5 = 0.f, a6 = 0.f, a7 = 0.f;
    for (int p = p0; p < p0 + 128; p += 8) {
      a0 += partials[(size_t)(p + 0) * H_DIM + c];
      a1 += partials[(size_t)(p + 1) * H_DIM + c];
      a2 += partials[(size_t)(p + 2) * H_DIM + c];
      a3 += partials[(size_t)(p + 3) * H_DIM + c];
      a4 += partials[(size_t)(p + 4) * H_DIM + c];
      a5 += partials[(size_t)(p + 5) * H_DIM + c];
      a6 += partials[(size_t)(p + 6) * H_DIM + c];
      a7 += partials[(size_t)(p + 7) * H_DIM + c];
    }
    float s = ((a0 + a1) + (a2 + a3)) + ((a4 + a5) + (a6 + a7));
    atomicAdd(hsum + c, s);
    return;
  }

  // --- GEMM role ---
  const int gb = bid - 64;
  const int wave = t >> 6, lane = t & 63;
  const int lrow = lane & 15, lquad = lane >> 4;
  const int wm = wave >> 1, wn = wave & 1;
  const int row0 = (gb & 31) * BM;
  const int col0 = (gb >> 5) * BN;

  f32x4 acc[4][4] = {};

  const int srow = lane >> 3;           // row within the 8-row group
  const int schunk = (lane & 7) ^ srow; // XOR-swizzled source chunk
  const u16* agbase = chb  + (size_t)(row0 + wave * 32 + srow) * H_DIM + schunk * 8;
  const u16* bgbase = wfhb + (size_t)(col0 + wave * 32 + srow) * H_DIM + schunk * 8;

#define STAGE(buf, kb)                                                        \
  do {                                                                        \
    _Pragma("unroll")                                                         \
    for (int i = 0; i < 4; ++i)                                               \
      __builtin_amdgcn_global_load_lds(                                       \
          (const __attribute__((address_space(1))) void*)(agbase + (size_t)i * 8 * H_DIM + (kb) * BK), \
          (__attribute__((address_space(3))) void*)(&As[buf][(wave * 32 + i * 8) * 64]), \
          16, 0, 0);                                                          \
    _Pragma("unroll")                                                         \
    for (int i = 0; i < 4; ++i)                                               \
      __builtin_amdgcn_global_load_lds(                                       \
          (const __attribute__((address_space(1))) void*)(bgbase + (size_t)i * 8 * H_DIM + (kb) * BK), \
          (__attribute__((address_space(3))) void*)(&Bs[buf][(wave * 32 + i * 8) * 64]), \
          16, 0, 0);                                                          \
  } while (0)

#define COMPUTE(buf)                                                          \
  do {                                                                        \
    _Pragma("unroll")                                                         \
    for (int step = 0; step < 2; ++step) {                                    \
      const int slot = ((step * 4 + lquad) ^ (lrow & 7)) * 8;                 \
      bf16x8 fa[4], fb[4];                                                    \
      _Pragma("unroll")                                                       \
      for (int i = 0; i < 4; ++i)                                             \
        fa[i] = *(const bf16x8*)(&As[buf][(wm * 64 + i * 16 + lrow) * 64 + slot]); \
      _Pragma("unroll")                                                       \
      for (int i = 0; i < 4; ++i)                                             \
        fb[i] = *(const bf16x8*)(&Bs[buf][(wn * 64 + i * 16 + lrow) * 64 + slot]); \
      _Pragma("unroll")                                                       \
      for (int mi = 0; mi < 4; ++mi)                                          \
        _Pragma("unroll")                                                     \
        for (int ni = 0; ni < 4; ++ni)                                        \
          acc[mi][ni] = __builtin_amdgcn_mfma_f32_16x16x32_bf16(              \
              fa[mi], fb[ni], acc[mi][ni], 0, 0, 0);                          \
    }                                                                         \
  } while (0)

  // prologue: tile 0 into buf 0
  STAGE(0, 0);
  __syncthreads();  // vmcnt(0) drain -> buf0 ready

  for (int kb = 0; kb < D_IN / BK - 1; ++kb) {
    const int cur = kb & 1;
    STAGE(cur ^ 1, kb + 1);  // issue next-tile loads BEFORE compute
    COMPUTE(cur);
    __syncthreads();         // drains vmcnt(0): buf^1 ready; all reads of buf done
  }
  COMPUTE(1);  // kb = 31 -> cur = 1, no prefetch

  // Epilogue. C/D layout: col = lane&15, row = (lane>>4)*4 + reg.
#pragma unroll
  for (int ni = 0; ni < 4; ++ni) {
    const int colg = col0 + wn * 64 + ni * 16 + lrow;
    const float gv = g[colg];
    float s = 0.f;
#pragma unroll
    for (int mi = 0; mi < 4; ++mi) {
      const int rowg = row0 + wm * 64 + mi * 16 + lquad * 4;
#pragma unroll
      for (int r = 0; r < 4; ++r) {
        float f = sigmoidf(gv + acc[mi][ni][r]);
        s += f * cc[(size_t)(rowg + r) * H_DIM + colg];
      }
    }
    s += __shfl_xor(s, 16);
    s += __shfl_xor(s, 32);
    if (lquad == 0) atomicAdd(accv + colg, s);
  }
#undef STAGE
#undef COMPUTE
}

// ---------------------------------------------------------------------------
// kmv2: iou[row] = ioux[row] + W_iou_h[row]·hsum. LDS-free, tiny VGPR ->
// 32 waves/CU streaming (the round-1 fused version starved this at 1.1 TB/s).
// ---------------------------------------------------------------------------
__global__ __launch_bounds__(256) void kmv2(const float* __restrict__ Wih,
                                            const float* __restrict__ hsum,
                                            float* __restrict__ iou) {
  const int wave = threadIdx.x >> 6, lane = threadIdx.x & 63;
  const int row = blockIdx.x * 4 + wave;  // 0..6143
  const float4* w = (const float4*)(Wih + (size_t)row * H_DIM);
  const float4* hv = (const float4*)hsum;
  float s = 0.f;
#pragma unroll
  for (int i = 0; i < 8; ++i) {
    int idx = i * 64 + lane;
    float4 a = w[idx], b = hv[idx];
    s += a.x * b.x + a.y * b.y + a.z * b.z + a.w * b.w;
  }
#pragma unroll
  for (int off = 32; off > 0; off >>= 1) s += __shfl_xor(s, off);
  if (lane == 0) iou[row] += s;
}

// ---------------------------------------------------------------------------
// kfinal: finalize (fp32 out, unchanged).
// ---------------------------------------------------------------------------
__global__ __launch_bounds__(256) void kfinal(const float* __restrict__ iou,
                                              const float* __restrict__ accv,
                                              float* __restrict__ out) {
  const int h = blockIdx.x * 256 + threadIdx.x;
  float si = sigmoidf(iou[h]);
  float so = sigmoidf(iou[H_DIM + h]);
  float tu = tanhf(iou[2 * H_DIM + h]);
  float c = si * tu + accv[h];
  float hh = so * tanhf(c);
  out[h] = so;
  out[H_DIM + h] = c;
  out[2 * H_DIM + h] = hh;
}

extern "C" void kernel_launch(void* const* d_in, const int* in_sizes, int n_in,
                              void* d_out, int out_size, void* d_ws, size_t ws_size,
                              hipStream_t stream) {
  const float* x   = (const float*)d_in[0];   // input [2048]
  const float* cc  = (const float*)d_in[1];   // children_c [4096,2048]
  const float* ch  = (const float*)d_in[2];   // children_h [4096,2048]
  const float* Wix = (const float*)d_in[3];   // W_iou_x [6144,2048]
  const float* bix = (const float*)d_in[4];   // b_iou_x [6144]
  const float* Wih = (const float*)d_in[5];   // W_iou_h [6144,2048]
  const float* bih = (const float*)d_in[6];   // b_iou_h [6144]
  const float* Wfx = (const float*)d_in[7];   // W_fx [2048,2048]
  const float* bfx = (const float*)d_in[8];   // b_fx [2048]
  const float* Wfh = (const float*)d_in[9];   // W_fh [2048,2048]
  const float* bfh = (const float*)d_in[10];  // b_fh [2048]

  float* ws   = (float*)d_ws;
  float* hsum = ws;                    // [2048]  (zeroed in k1; kG atomics)
  float* iou  = ws + 2048;             // [6144]  (ioux written by k1; += in kmv2)
  float* g    = ws + 8192;             // [2048]
  float* accv = ws + 10240;            // [2048]  (zeroed in k1; kG atomics)
  float* partials = ws + 12288;        // [1024 * 2048]
  u16* chb  = (u16*)(ws + 12288 + 1024 * 2048);  // [4096*2048] bf16
  u16* wfhb = chb + (size_t)K_CH * H_DIM;        // [2048*2048] bf16
  float* out = (float*)d_out;

  k1<<<3585, 256, 0, stream>>>(ch, Wfh, Wfx, bfx, bfh, x, Wix, bix, bih,
                               partials, chb, wfhb, g, iou, hsum, accv);
  kG<<<576, 256, 0, stream>>>(chb, cc, wfhb, g, partials, hsum, accv);
  kmv2<<<1536, 256, 0, stream>>>(Wih, hsum, iou);
  kfinal<<<8, 256, 0, stream>>>(iou, accv, out);
}